// Round 1
// baseline (7553.552 us; speedup 1.0000x reference)
//
#include <hip/hip_runtime.h>
#include <hip/hip_bf16.h>
#include <math.h>

// Problem dims
#define BATCH 256
#define SEQ   512
#define IN_D  512
#define HID   512
#define FOURH 2048

typedef __bf16 bf16x8 __attribute__((ext_vector_type(8)));
typedef float  f32x4  __attribute__((ext_vector_type(4)));

// ---------------------------------------------------------------------------
// Init: convert weights to bf16, fuse biases, zero h/c state.
// ---------------------------------------------------------------------------
__global__ __launch_bounds__(256) void init_kernel(
    const float* __restrict__ W_all_w, const float* __restrict__ W_all_b,
    const float* __restrict__ U_all_w, const float* __restrict__ U_all_b,
    const float* __restrict__ W_d_w,
    __bf16* __restrict__ Wb, __bf16* __restrict__ Ub, __bf16* __restrict__ Db,
    float* __restrict__ bias_all,
    __bf16* __restrict__ h_bf, __bf16* __restrict__ c_bf,
    float* __restrict__ c_master)
{
    const int stride = gridDim.x * blockDim.x;
    const int tid0 = blockIdx.x * blockDim.x + threadIdx.x;

    const int nW = FOURH * HID;          // 2048*512
    for (int i = tid0; i < nW; i += stride) {
        Wb[i] = (__bf16)W_all_w[i];
        Ub[i] = (__bf16)U_all_w[i];
    }
    const int nD = HID * HID;            // 512*512
    for (int i = tid0; i < nD; i += stride) {
        Db[i] = (__bf16)W_d_w[i];
    }
    for (int i = tid0; i < FOURH; i += stride) {
        bias_all[i] = W_all_b[i] + U_all_b[i];
    }
    const int nS = BATCH * HID;          // 256*512
    for (int i = tid0; i < nS; i += stride) {
        h_bf[i] = (__bf16)0.0f;
        c_bf[i] = (__bf16)0.0f;
        c_master[i] = 0.0f;
    }
}

// ---------------------------------------------------------------------------
// Per-step GEMM:
//   col-blocks 0..31  : outs[b, g] = sum_j h[b,j] W_all[g,j] + sum_j x[b,j] U_all[g,j] + bias_all[g]
//   col-blocks 32..39 : d[b, k]    = sum_j c[b,j] W_d[k,j] + (bias added in gate_update? no: here)
// grid = dim3(40, 16), block = 256 (4 waves). Tile: M=16 (batch), N=64, BK=128.
// ---------------------------------------------------------------------------
__global__ __launch_bounds__(256) void step_gemm(
    const __bf16* __restrict__ h_bf,     // [256][512]
    const __bf16* __restrict__ c_bf,     // [256][512]
    const float* __restrict__ x,         // inputs [256][512][512]
    const __bf16* __restrict__ Wb,       // [2048][512]
    const __bf16* __restrict__ Ub,       // [2048][512]
    const __bf16* __restrict__ Db,       // [512][512]
    const float* __restrict__ bias_all,  // [2048]
    const float* __restrict__ Wd_b,      // [512]
    float* __restrict__ outs_raw,        // [256][2048]
    float* __restrict__ d_raw,           // [256][512]
    int t)
{
    const int cb  = blockIdx.x;   // 0..39
    const int bg  = blockIdx.y;   // 0..15
    const int tid = threadIdx.x;
    const int wave = tid >> 6;
    const int lane = tid & 63;

    const bool is_d = (cb >= 32);
    const int col0  = is_d ? (cb - 32) * 64 : cb * 64;
    const int KTOT  = is_d ? HID : (HID + IN_D);   // 512 or 1024

    __shared__ __bf16 As[16][128];
    __shared__ __bf16 Bs[64][128];

    f32x4 acc = {0.f, 0.f, 0.f, 0.f};

    const int a_row = tid >> 4;          // 0..15
    const int a_k0  = (tid & 15) * 8;    // 0..120
    const int a_swz = (a_row & 7) << 3;
    const int b_row = tid >> 2;          // 0..63
    const int b_k0  = (tid & 3) * 32;    // 0,32,64,96
    const int b_swz = (b_row & 7) << 3;

    const int lrow = lane & 15;
    const int kq   = lane >> 4;          // 0..3
    const int swzA = (lrow & 7) << 3;
    const int swzB = swzA;               // same row-low-bits rule

    for (int kk = 0; kk < KTOT; kk += 128) {
        // ---- stage A tile [16][128] ----
        {
            const int b = bg * 16 + a_row;
            const int kg = kk + a_k0;
            if (is_d) {
                const uint4* s = reinterpret_cast<const uint4*>(c_bf + b * HID + kg);
                *reinterpret_cast<uint4*>(&As[a_row][a_k0 ^ a_swz]) = *s;
            } else if (kg < HID) {
                const uint4* s = reinterpret_cast<const uint4*>(h_bf + b * HID + kg);
                *reinterpret_cast<uint4*>(&As[a_row][a_k0 ^ a_swz]) = *s;
            } else {
                const float* xs = x + ((size_t)b * SEQ + t) * IN_D + (kg - HID);
                float4 v0 = *reinterpret_cast<const float4*>(xs);
                float4 v1 = *reinterpret_cast<const float4*>(xs + 4);
                __bf16* d = &As[a_row][a_k0 ^ a_swz];
                d[0] = (__bf16)v0.x; d[1] = (__bf16)v0.y;
                d[2] = (__bf16)v0.z; d[3] = (__bf16)v0.w;
                d[4] = (__bf16)v1.x; d[5] = (__bf16)v1.y;
                d[6] = (__bf16)v1.z; d[7] = (__bf16)v1.w;
            }
        }
        // ---- stage B tile [64][128] (weights are [N,K] row-major = B^T) ----
        {
            const int g = col0 + b_row;
            const __bf16* src;
            if (is_d)            src = Db + (size_t)g * HID + kk;
            else if (kk < HID)   src = Wb + (size_t)g * HID + kk;
            else                 src = Ub + (size_t)g * HID + (kk - HID);
            #pragma unroll
            for (int j = 0; j < 4; ++j) {
                const int ke = b_k0 + j * 8;
                *reinterpret_cast<uint4*>(&Bs[b_row][ke ^ b_swz]) =
                    *reinterpret_cast<const uint4*>(src + ke);
            }
        }
        __syncthreads();

        // ---- MFMA: 4 × 16x16x32 per wave per iter ----
        #pragma unroll
        for (int k2 = 0; k2 < 4; ++k2) {
            const int ke = k2 * 32 + kq * 8;
            bf16x8 a = *reinterpret_cast<const bf16x8*>(&As[lrow][ke ^ swzA]);
            bf16x8 bb = *reinterpret_cast<const bf16x8*>(&Bs[wave * 16 + lrow][ke ^ swzB]);
            acc = __builtin_amdgcn_mfma_f32_16x16x32_bf16(a, bb, acc, 0, 0, 0);
        }
        __syncthreads();
    }

    // ---- epilogue: C/D layout col=lane&15, row=(lane>>4)*4+r ----
    const int col = col0 + wave * 16 + (lane & 15);
    const int row0 = (lane >> 4) * 4;
    const float bias = is_d ? Wd_b[col] : bias_all[col];
    #pragma unroll
    for (int r = 0; r < 4; ++r) {
        const int b = bg * 16 + row0 + r;
        const float v = acc[r] + bias;
        if (is_d) d_raw[b * HID + col] = v;
        else      outs_raw[b * FOURH + col] = v;
    }
}

// ---------------------------------------------------------------------------
// Per-step gate update (elementwise recurrence).
// grid = 512 blocks x 256 threads = 131072 = BATCH*HID
// ---------------------------------------------------------------------------
__global__ __launch_bounds__(256) void gate_update(
    const float* __restrict__ outs_raw,   // [256][2048]
    const float* __restrict__ d_raw,      // [256][512]
    const float* __restrict__ timestamps, // [256][512]
    float* __restrict__ c_master,         // [256][512]
    __bf16* __restrict__ h_bf,            // [256][512]
    __bf16* __restrict__ c_bf,            // [256][512]
    float* __restrict__ out,              // outputs + h + c
    int t)
{
    const int gid = blockIdx.x * 256 + threadIdx.x;  // 0..131071
    const int b = gid >> 9;
    const int k = gid & 511;

    const float fo = outs_raw[b * FOURH + k];
    const float io = outs_raw[b * FOURH + 512 + k];
    const float oo = outs_raw[b * FOURH + 1024 + k];
    const float ct = outs_raw[b * FOURH + 1536 + k];
    const float dd = d_raw[gid];
    const float c_old = c_master[gid];
    const float tt = timestamps[b * SEQ + t];

    const float c_s1  = tanhf(dd);
    const float c_adj = c_old - c_s1 + c_s1 * tt;
    const float f = 1.0f / (1.0f + expf(-fo));
    const float i = 1.0f / (1.0f + expf(-io));
    const float o = 1.0f / (1.0f + expf(-oo));
    const float c_tmp = tanhf(ct);
    const float c_new = f * c_adj + i * c_tmp;
    const float h_new = o * tanhf(c_new);

    c_master[gid] = c_new;
    h_bf[gid] = (__bf16)h_new;
    c_bf[gid] = (__bf16)c_new;

    out[((size_t)b * SEQ + t) * HID + k] = o;
    if (t == SEQ - 1) {
        const size_t base = (size_t)BATCH * SEQ * HID;  // 67108864
        out[base + gid] = h_new;
        out[base + (size_t)BATCH * HID + gid] = c_new;
    }
}

// ---------------------------------------------------------------------------
extern "C" void kernel_launch(void* const* d_in, const int* in_sizes, int n_in,
                              void* d_out, int out_size, void* d_ws, size_t ws_size,
                              hipStream_t stream) {
    const float* inputs     = (const float*)d_in[0];
    const float* timestamps = (const float*)d_in[1];
    const float* W_all_w    = (const float*)d_in[2];
    const float* W_all_b    = (const float*)d_in[3];
    const float* U_all_w    = (const float*)d_in[4];
    const float* U_all_b    = (const float*)d_in[5];
    const float* W_d_w      = (const float*)d_in[6];
    const float* W_d_b      = (const float*)d_in[7];
    float* out = (float*)d_out;

    char* ws = (char*)d_ws;
    size_t off = 0;
    auto alloc = [&](size_t bytes) -> void* {
        void* p = ws + off;
        off += (bytes + 255) & ~(size_t)255;
        return p;
    };
    __bf16* Wb       = (__bf16*)alloc((size_t)FOURH * HID * 2);
    __bf16* Ub       = (__bf16*)alloc((size_t)FOURH * HID * 2);
    __bf16* Db       = (__bf16*)alloc((size_t)HID * HID * 2);
    float*  bias_all = (float*) alloc((size_t)FOURH * 4);
    __bf16* h_bf     = (__bf16*)alloc((size_t)BATCH * HID * 2);
    __bf16* c_bf     = (__bf16*)alloc((size_t)BATCH * HID * 2);
    float*  c_master = (float*) alloc((size_t)BATCH * HID * 4);
    float*  outs_raw = (float*) alloc((size_t)BATCH * FOURH * 4);
    float*  d_raw    = (float*) alloc((size_t)BATCH * HID * 4);

    hipLaunchKernelGGL(init_kernel, dim3(1024), dim3(256), 0, stream,
                       W_all_w, W_all_b, U_all_w, U_all_b, W_d_w,
                       Wb, Ub, Db, bias_all, h_bf, c_bf, c_master);

    for (int t = 0; t < SEQ; ++t) {
        hipLaunchKernelGGL(step_gemm, dim3(40, 16), dim3(256), 0, stream,
                           h_bf, c_bf, inputs, Wb, Ub, Db, bias_all, W_d_b,
                           outs_raw, d_raw, t);
        hipLaunchKernelGGL(gate_update, dim3(512), dim3(256), 0, stream,
                           outs_raw, d_raw, timestamps, c_master, h_bf, c_bf,
                           out, t);
    }
}